// Round 1
// baseline (22994.444 us; speedup 1.0000x reference)
//
#include <hip/hip_runtime.h>
#include <math.h>

// ---- problem constants ----
#define NB   64      // batch
#define TT   150     // timesteps
#define CIN  150
#define HH   1024
#define G3   3072    // 3*H
#define NCOL 6144    // 2*3072 (both directions)
#define KP0  160     // CIN padded to mult of 32
#define RT   9600    // T*N rows
#define NC   60

using bf16x8 = __attribute__((ext_vector_type(8))) __bf16;
using f32x4  = __attribute__((ext_vector_type(4))) float;

static __device__ __forceinline__ unsigned short f2bf(float f){
  unsigned int x = __builtin_bit_cast(unsigned int, f);
  x += 0x7fffu + ((x >> 16) & 1u);          // RNE
  return (unsigned short)(x >> 16);
}
static __device__ __forceinline__ float bf2f(unsigned short u){
  unsigned int x = ((unsigned int)u) << 16;
  return __builtin_bit_cast(float, x);
}
static __device__ __forceinline__ float sigmoidf(float x){
  return 1.0f / (1.0f + expf(-x));
}

// ---- BatchNorm stats: one block per channel ----
__global__ void bn_stats(const float* __restrict__ x, const float* __restrict__ gamma,
                         const float* __restrict__ beta, float* __restrict__ ss){
  const int c = blockIdx.x;
  float s = 0.f, s2 = 0.f;
  for (int i = threadIdx.x; i < RT; i += 256){
    float v = x[(size_t)i * CIN + c];
    s += v; s2 += v * v;
  }
  __shared__ float sh1[256], sh2[256];
  sh1[threadIdx.x] = s; sh2[threadIdx.x] = s2;
  __syncthreads();
  for (int st = 128; st > 0; st >>= 1){
    if ((int)threadIdx.x < st){
      sh1[threadIdx.x] += sh1[threadIdx.x + st];
      sh2[threadIdx.x] += sh2[threadIdx.x + st];
    }
    __syncthreads();
  }
  if (threadIdx.x == 0){
    float mean = sh1[0] * (1.f / RT);
    float var  = sh2[0] * (1.f / RT) - mean * mean;
    float sc   = rsqrtf(var + 1e-5f) * gamma[c];
    ss[c]       = sc;
    ss[CIN + c] = beta[c] - mean * sc;
  }
}

// ---- normalize + transpose [N,T,C] -> bf16 [t*64+n, KP0] with zero pad ----
__global__ void bn_apply(const float* __restrict__ x, const float* __restrict__ ss,
                         unsigned short* __restrict__ xn){
  int idx = blockIdx.x * 256 + threadIdx.x;
  if (idx >= RT * KP0) return;
  int r = idx / KP0, c = idx - r * KP0;
  int t = r >> 6, n = r & 63;
  float v = 0.f;
  if (c < CIN) v = x[((size_t)n * TT + t) * CIN + c] * ss[c] + ss[CIN + c];
  xn[idx] = f2bf(v);
}

// ---- cast fp32 -> bf16 (grid stride) ----
__global__ void cast_bf(const float* __restrict__ s, unsigned short* __restrict__ d, int n){
  for (int i = blockIdx.x * 256 + threadIdx.x; i < n; i += gridDim.x * 256)
    d[i] = f2bf(s[i]);
}

// ---- cast + pad w_ih0 [6144,150] -> [6144,160] bf16 ----
__global__ void cast_pad_w0(const float* __restrict__ w, unsigned short* __restrict__ d){
  int idx = blockIdx.x * 256 + threadIdx.x;
  if (idx >= NCOL * KP0) return;
  int row = idx / KP0, c = idx - row * KP0;
  d[idx] = (c < CIN) ? f2bf(w[(size_t)row * CIN + c]) : (unsigned short)0;
}

__global__ void zero16(uint4* p, int n){
  int i = blockIdx.x * 256 + threadIdx.x;
  if (i < n) p[i] = make_uint4(0u, 0u, 0u, 0u);
}

__global__ void guard_k(float* out){ out[0] = -12345.0f; }

// ---- gi GEMM: C[r, col] = sum_k A[r,k]*B[col,k] + bias[col], bf16 in/out, f32 acc
// grid (150, 96), block 256. Tile 64(M) x 64(N); wave w covers 16 cols.
__global__ __launch_bounds__(256) void gemm_gi(
    const unsigned short* __restrict__ A, const unsigned short* __restrict__ B,
    const float* __restrict__ bias, unsigned short* __restrict__ C, int K)
{
  const int r0 = blockIdx.x * 64;
  const int c0 = blockIdx.y * 64;
  const int w  = threadIdx.x >> 6;
  const int l  = threadIdx.x & 63;
  const int lr = l & 15;
  const int lk = (l >> 4) * 8;
  const int col = c0 + 16 * w + lr;

  f32x4 acc[4] = {f32x4{0,0,0,0}, f32x4{0,0,0,0}, f32x4{0,0,0,0}, f32x4{0,0,0,0}};
  const unsigned short* Ab = A + (size_t)(r0 + lr) * K + lk;
  const unsigned short* Bb = B + (size_t)col * K + lk;

  for (int k0 = 0; k0 < K; k0 += 32){
    bf16x8 b = *(const bf16x8*)(Bb + k0);
#pragma unroll
    for (int mt = 0; mt < 4; ++mt){
      bf16x8 a = *(const bf16x8*)(Ab + (size_t)mt * 16 * K + k0);
      acc[mt] = __builtin_amdgcn_mfma_f32_16x16x32_bf16(a, b, acc[mt], 0, 0, 0);
    }
  }
  const float bv = bias[col];
  const int rb = (l >> 4) * 4;
#pragma unroll
  for (int mt = 0; mt < 4; ++mt){
#pragma unroll
    for (int reg = 0; reg < 4; ++reg){
      int row = r0 + 16 * mt + rb + reg;
      C[(size_t)row * NCOL + col] = f2bf(acc[mt][reg] + bv);
    }
  }
}

// ---- one recurrent step: gh GEMM (3 gates together) + gate math + h update
// grid (16 jgroups, 2 dirs), block 256. Wave w covers j-strip of 16, all 64 batch rows.
__global__ __launch_bounds__(256) void gru_step(
    const unsigned short* __restrict__ hbf_prev, const float* __restrict__ hf_prev,
    float* __restrict__ hf_next, unsigned short* __restrict__ hbf_next,
    const unsigned short* __restrict__ whh, const float* __restrict__ bhh,
    const unsigned short* __restrict__ gi, unsigned short* __restrict__ outb,
    int t, int wout)
{
  const int jg = blockIdx.x;
  const int d  = blockIdx.y;
  const int w  = threadIdx.x >> 6;
  const int l  = threadIdx.x & 63;
  const int lr = l & 15;
  const int lk = (l >> 4) * 8;
  const int jcol = jg * 64 + 16 * w + lr;   // 0..1023

  f32x4 accr[4] = {f32x4{0,0,0,0}, f32x4{0,0,0,0}, f32x4{0,0,0,0}, f32x4{0,0,0,0}};
  f32x4 accz[4] = {f32x4{0,0,0,0}, f32x4{0,0,0,0}, f32x4{0,0,0,0}, f32x4{0,0,0,0}};
  f32x4 accn[4] = {f32x4{0,0,0,0}, f32x4{0,0,0,0}, f32x4{0,0,0,0}, f32x4{0,0,0,0}};

  const unsigned short* hA = hbf_prev + (size_t)d * (NB * HH) + (size_t)lr * HH + lk;
  const unsigned short* wB = whh + (size_t)d * (G3 * HH) + (size_t)jcol * HH + lk;

  for (int k0 = 0; k0 < HH; k0 += 32){
    bf16x8 br  = *(const bf16x8*)(wB + k0);
    bf16x8 bz  = *(const bf16x8*)(wB + (size_t)HH * HH + k0);
    bf16x8 bn_ = *(const bf16x8*)(wB + (size_t)2 * HH * HH + k0);
#pragma unroll
    for (int mt = 0; mt < 4; ++mt){
      bf16x8 a = *(const bf16x8*)(hA + (size_t)mt * 16 * HH + k0);
      accr[mt] = __builtin_amdgcn_mfma_f32_16x16x32_bf16(a, br,  accr[mt], 0, 0, 0);
      accz[mt] = __builtin_amdgcn_mfma_f32_16x16x32_bf16(a, bz,  accz[mt], 0, 0, 0);
      accn[mt] = __builtin_amdgcn_mfma_f32_16x16x32_bf16(a, bn_, accn[mt], 0, 0, 0);
    }
  }

  const float bhr = bhh[d * G3 + jcol];
  const float bhz = bhh[d * G3 + HH + jcol];
  const float bhn = bhh[d * G3 + 2 * HH + jcol];
  const int rb = (l >> 4) * 4;

#pragma unroll
  for (int mt = 0; mt < 4; ++mt){
#pragma unroll
    for (int reg = 0; reg < 4; ++reg){
      int n = 16 * mt + rb + reg;
      size_t hidx  = (size_t)(d * NB + n) * HH + jcol;
      size_t gbase = (size_t)(t * NB + n) * NCOL + (size_t)d * G3 + jcol;
      float gr = bf2f(gi[gbase]);
      float gz = bf2f(gi[gbase + HH]);
      float gn = bf2f(gi[gbase + 2 * HH]);
      float hold = hf_prev[hidx];
      float r  = sigmoidf(gr + accr[mt][reg] + bhr);
      float z  = sigmoidf(gz + accz[mt][reg] + bhz);
      float nn = tanhf(gn + r * (accn[mt][reg] + bhn));
      float hn = (1.f - z) * nn + z * hold;
      hf_next[hidx] = hn;
      unsigned short hb_ = f2bf(hn);
      hbf_next[hidx] = hb_;
      if (wout) outb[(size_t)(t * NB + n) * (2 * HH) + (size_t)d * HH + jcol] = hb_;
    }
  }
}

// ---- final FC: out[n,c] = sum_k last[n,k]*fw[c,k] + fb[c]; last from fp32 h state
__global__ void fc_kernel(const float* __restrict__ hf, const float* __restrict__ fw,
                          const float* __restrict__ fb, float* __restrict__ out){
  int b = blockIdx.x;               // 0..3839
  int n = b / NC, c = b - n * NC;
  int l = threadIdx.x;              // 64 threads
  float s = 0.f;
  for (int k = l; k < 2 * HH; k += 64){
    float hv = (k < HH) ? hf[(size_t)n * HH + k]
                        : hf[(size_t)(NB + n) * HH + (k - HH)];
    s += hv * fw[(size_t)c * (2 * HH) + k];
  }
#pragma unroll
  for (int off = 32; off > 0; off >>= 1) s += __shfl_down(s, off);
  if (l == 0) out[n * NC + c] = s + fb[c];
}

extern "C" void kernel_launch(void* const* d_in, const int* in_sizes, int n_in,
                              void* d_out, int out_size, void* d_ws, size_t ws_size,
                              hipStream_t stream)
{
  const float* x      = (const float*)d_in[0];
  const float* gamma  = (const float*)d_in[1];
  const float* beta   = (const float*)d_in[2];
  const float* w_ih0  = (const float*)d_in[3];
  const float* w_hh0  = (const float*)d_in[4];
  const float* b_ih0  = (const float*)d_in[5];
  const float* b_hh0  = (const float*)d_in[6];
  const float* w_ih   = (const float*)d_in[7];
  const float* w_hh   = (const float*)d_in[8];
  const float* b_ih   = (const float*)d_in[9];
  const float* b_hh   = (const float*)d_in[10];
  const float* fc_w   = (const float*)d_in[11];
  const float* fc_b   = (const float*)d_in[12];
  float* out = (float*)d_out;

  char* ws = (char*)d_ws;
  size_t off = 0;
  auto alloc = [&](size_t bytes)->void*{
    void* p = ws + off; off += (bytes + 255) & ~(size_t)255; return p;
  };
  unsigned short* whh_bf = (unsigned short*)alloc((size_t)3 * 2 * G3 * HH * 2);   // 37.75MB
  unsigned short* w0_bf  = (unsigned short*)alloc((size_t)NCOL * KP0 * 2);        // 1.97MB
  unsigned short* wih_bf = (unsigned short*)alloc((size_t)2 * NCOL * 2 * HH * 2); // 50.3MB
  unsigned short* xn_bf  = (unsigned short*)alloc((size_t)RT * KP0 * 2);          // 3.07MB
  unsigned short* gi_bf  = (unsigned short*)alloc((size_t)RT * NCOL * 2);         // 118MB
  unsigned short* out0   = (unsigned short*)alloc((size_t)RT * 2 * HH * 2);       // 39.3MB
  unsigned short* out1   = (unsigned short*)alloc((size_t)RT * 2 * HH * 2);       // 39.3MB
  float* hf0 = (float*)alloc((size_t)2 * NB * HH * 4);
  float* hf1 = (float*)alloc((size_t)2 * NB * HH * 4);
  unsigned short* hb0 = (unsigned short*)alloc((size_t)2 * NB * HH * 2);
  unsigned short* hb1 = (unsigned short*)alloc((size_t)2 * NB * HH * 2);
  float* ss = (float*)alloc(2048);

  if (off > ws_size){ guard_k<<<1, 1, 0, stream>>>(out); return; }

  // BN + casts
  bn_stats<<<CIN, 256, 0, stream>>>(x, gamma, beta, ss);
  bn_apply<<<(RT * KP0 + 255) / 256, 256, 0, stream>>>(x, ss, xn_bf);
  cast_pad_w0<<<(NCOL * KP0 + 255) / 256, 256, 0, stream>>>(w_ih0, w0_bf);
  cast_bf<<<4096, 256, 0, stream>>>(w_hh0, whh_bf, 2 * G3 * HH);
  cast_bf<<<4096, 256, 0, stream>>>(w_hh,  whh_bf + (size_t)2 * G3 * HH, 2 * 2 * G3 * HH);
  cast_bf<<<4096, 256, 0, stream>>>(w_ih,  wih_bf, 2 * NCOL * 2 * HH);

  float* hfbuf[2] = {hf0, hf1};
  unsigned short* hbbuf[2] = {hb0, hb1};

  for (int lyr = 0; lyr < 3; ++lyr){
    if (lyr == 0){
      gemm_gi<<<dim3(RT / 64, NCOL / 64), 256, 0, stream>>>(xn_bf, w0_bf, b_ih0, gi_bf, KP0);
    } else {
      const unsigned short* Ain = (lyr == 1) ? out0 : out1;
      gemm_gi<<<dim3(RT / 64, NCOL / 64), 256, 0, stream>>>(
          Ain, wih_bf + (size_t)(lyr - 1) * NCOL * 2 * HH,
          b_ih + (size_t)(lyr - 1) * NCOL, gi_bf, 2 * HH);
    }
    zero16<<<(2 * NB * HH * 4 / 16 + 255) / 256, 256, 0, stream>>>((uint4*)hf0, 2 * NB * HH * 4 / 16);
    zero16<<<(2 * NB * HH * 2 / 16 + 255) / 256, 256, 0, stream>>>((uint4*)hb0, 2 * NB * HH * 2 / 16);

    const unsigned short* whh_l = whh_bf + (size_t)lyr * 2 * G3 * HH;
    const float* bhh_l = (lyr == 0) ? b_hh0 : (b_hh + (size_t)(lyr - 1) * NCOL);
    unsigned short* outb = (lyr == 0) ? out0 : out1;
    int wout = (lyr < 2) ? 1 : 0;
    for (int t = 0; t < TT; ++t){
      gru_step<<<dim3(16, 2), 256, 0, stream>>>(
          hbbuf[t & 1], hfbuf[t & 1], hfbuf[(t + 1) & 1], hbbuf[(t + 1) & 1],
          whh_l, bhh_l, gi_bf, outb, t, wout);
    }
  }
  fc_kernel<<<NB * NC, 64, 0, stream>>>(hf0, fc_w, fc_b, out);
}

// Round 2
// 20109.970 us; speedup vs baseline: 1.1434x; 1.1434x over previous
//
#include <hip/hip_runtime.h>
#include <math.h>

// ---- problem constants ----
#define NB   64      // batch
#define TT   150     // timesteps
#define CIN  150
#define HH   1024
#define G3   3072    // 3*H
#define NCOL 6144    // 2*3072 (both directions)
#define KP0  160     // CIN padded to mult of 32
#define RT   9600    // T*N rows
#define NC   60

using bf16x8 = __attribute__((ext_vector_type(8))) __bf16;
using f32x4  = __attribute__((ext_vector_type(4))) float;

static __device__ __forceinline__ unsigned short f2bf(float f){
  unsigned int x = __builtin_bit_cast(unsigned int, f);
  x += 0x7fffu + ((x >> 16) & 1u);          // RNE
  return (unsigned short)(x >> 16);
}
static __device__ __forceinline__ float bf2f(unsigned short u){
  unsigned int x = ((unsigned int)u) << 16;
  return __builtin_bit_cast(float, x);
}
static __device__ __forceinline__ float sigmoidf(float x){
  return 1.0f / (1.0f + expf(-x));
}

// ---- BatchNorm stats: one block per channel ----
__global__ void bn_stats(const float* __restrict__ x, const float* __restrict__ gamma,
                         const float* __restrict__ beta, float* __restrict__ ss){
  const int c = blockIdx.x;
  float s = 0.f, s2 = 0.f;
  for (int i = threadIdx.x; i < RT; i += 256){
    float v = x[(size_t)i * CIN + c];
    s += v; s2 += v * v;
  }
  __shared__ float sh1[256], sh2[256];
  sh1[threadIdx.x] = s; sh2[threadIdx.x] = s2;
  __syncthreads();
  for (int st = 128; st > 0; st >>= 1){
    if ((int)threadIdx.x < st){
      sh1[threadIdx.x] += sh1[threadIdx.x + st];
      sh2[threadIdx.x] += sh2[threadIdx.x + st];
    }
    __syncthreads();
  }
  if (threadIdx.x == 0){
    float mean = sh1[0] * (1.f / RT);
    float var  = sh2[0] * (1.f / RT) - mean * mean;
    float sc   = rsqrtf(var + 1e-5f) * gamma[c];
    ss[c]       = sc;
    ss[CIN + c] = beta[c] - mean * sc;
  }
}

// ---- normalize + transpose [N,T,C] -> bf16 [t*64+n, KP0] with zero pad ----
__global__ void bn_apply(const float* __restrict__ x, const float* __restrict__ ss,
                         unsigned short* __restrict__ xn){
  int idx = blockIdx.x * 256 + threadIdx.x;
  if (idx >= RT * KP0) return;
  int r = idx / KP0, c = idx - r * KP0;
  int t = r >> 6, n = r & 63;
  float v = 0.f;
  if (c < CIN) v = x[((size_t)n * TT + t) * CIN + c] * ss[c] + ss[CIN + c];
  xn[idx] = f2bf(v);
}

// ---- cast fp32 -> bf16 (grid stride) ----
__global__ void cast_bf(const float* __restrict__ s, unsigned short* __restrict__ d, int n){
  for (int i = blockIdx.x * 256 + threadIdx.x; i < n; i += gridDim.x * 256)
    d[i] = f2bf(s[i]);
}

// ---- cast + pad w_ih0 [6144,150] -> [6144,160] bf16 ----
__global__ void cast_pad_w0(const float* __restrict__ w, unsigned short* __restrict__ d){
  int idx = blockIdx.x * 256 + threadIdx.x;
  if (idx >= NCOL * KP0) return;
  int row = idx / KP0, c = idx - row * KP0;
  d[idx] = (c < CIN) ? f2bf(w[(size_t)row * CIN + c]) : (unsigned short)0;
}

__global__ void zero16(uint4* p, int n){
  int i = blockIdx.x * 256 + threadIdx.x;
  if (i < n) p[i] = make_uint4(0u, 0u, 0u, 0u);
}

__global__ void guard_k(float* out){ out[0] = -12345.0f; }

// ---- gi GEMM: C[r, col] = sum_k A[r,k]*B[col,k] + bias[col], bf16 in/out, f32 acc
__global__ __launch_bounds__(256) void gemm_gi(
    const unsigned short* __restrict__ A, const unsigned short* __restrict__ B,
    const float* __restrict__ bias, unsigned short* __restrict__ C, int K)
{
  const int r0 = blockIdx.x * 64;
  const int c0 = blockIdx.y * 64;
  const int w  = threadIdx.x >> 6;
  const int l  = threadIdx.x & 63;
  const int lr = l & 15;
  const int lk = (l >> 4) * 8;
  const int col = c0 + 16 * w + lr;

  f32x4 acc[4] = {f32x4{0,0,0,0}, f32x4{0,0,0,0}, f32x4{0,0,0,0}, f32x4{0,0,0,0}};
  const unsigned short* Ab = A + (size_t)(r0 + lr) * K + lk;
  const unsigned short* Bb = B + (size_t)col * K + lk;

  for (int k0 = 0; k0 < K; k0 += 32){
    bf16x8 b = *(const bf16x8*)(Bb + k0);
#pragma unroll
    for (int mt = 0; mt < 4; ++mt){
      bf16x8 a = *(const bf16x8*)(Ab + (size_t)mt * 16 * K + k0);
      acc[mt] = __builtin_amdgcn_mfma_f32_16x16x32_bf16(a, b, acc[mt], 0, 0, 0);
    }
  }
  const float bv = bias[col];
  const int rb = (l >> 4) * 4;
#pragma unroll
  for (int mt = 0; mt < 4; ++mt){
#pragma unroll
    for (int reg = 0; reg < 4; ++reg){
      int row = r0 + 16 * mt + rb + reg;
      C[(size_t)row * NCOL + col] = f2bf(acc[mt][reg] + bv);
    }
  }
}

// ================= persistent GRU layer =================
// grid 128 = 2 dirs x 64 col-tiles (16 hidden cols each), block 256 (4 waves).
// Weights (3 gates x 16 cols x 1024) live in LDS (96KB, XOR-swizzled).
// Wave w computes batch tile mt=w (16 rows) for all 3 gates.
// MFMA: A = W[gc,k] (LDS), B = h[n,k] (global bf16), D[gc,n].
__global__ __launch_bounds__(256, 1) void gru_layer(
    const unsigned short* __restrict__ whh,   // [2][3072][1024] bf16
    const float* __restrict__ bhh,            // [2][3072]
    const unsigned short* __restrict__ gi,    // [9600][6144] bf16
    unsigned short* __restrict__ outb,        // [9600][2048] bf16 (may be unused)
    float* __restrict__ hf0, float* __restrict__ hf1,             // [2][64][1024] f32
    unsigned short* __restrict__ hb0, unsigned short* __restrict__ hb1, // bf16
    int* __restrict__ flags, int wout)
{
  const int d  = blockIdx.x >> 6;
  const int jt = blockIdx.x & 63;
  const int j0 = jt * 16;
  const int w  = threadIdx.x >> 6;
  const int l  = threadIdx.x & 63;
  const int lr = l & 15;
  const int hi = l >> 4;

  __shared__ unsigned char wlds[98304];   // 3 planes of 32KB: [16 rows][2048B], swizzled

  // ---- load weight slice to LDS (once per layer) ----
  {
    const unsigned short* wsrc = whh + (size_t)d * (G3 * HH);
    for (int c = threadIdx.x; c < 6144; c += 256){     // 16B chunks
      int g   = c >> 11;
      int rem = c & 2047;
      int r   = rem >> 7;
      int kc  = rem & 127;
      uint4 v = *(const uint4*)(wsrc + (size_t)(g * HH + j0 + r) * HH + kc * 8);
      int byteoff = (kc * 16) ^ ((r & 7) << 4);
      *(uint4*)(wlds + g * 32768 + r * 2048 + byteoff) = v;
    }
  }
  __syncthreads();

  // biases for this lane's 4 gate-cols (gc = j0 + hi*4 + reg)
  const float4 br4 = *(const float4*)(bhh + d * G3 +          j0 + hi * 4);
  const float4 bz4 = *(const float4*)(bhh + d * G3 + HH +     j0 + hi * 4);
  const float4 bn4 = *(const float4*)(bhh + d * G3 + 2 * HH + j0 + hi * 4);

  const int n    = w * 16 + lr;            // batch row this lane handles in epilogue
  const int jcol = j0 + hi * 4;            // first of 4 hidden cols this lane handles

  for (int t = 0; t < TT; ++t){
    const unsigned short* hprev = ((t & 1) ? hb1 : hb0) + (size_t)d * (NB * HH);
    const float*  hfprev = ((t & 1) ? hf1 : hf0) + (size_t)d * (NB * HH);
    float*        hfnext = ((t & 1) ? hf0 : hf1) + (size_t)d * (NB * HH);
    unsigned short* hbnext = ((t & 1) ? hb0 : hb1) + (size_t)d * (NB * HH);

    f32x4 ar = {0,0,0,0}, az = {0,0,0,0}, an = {0,0,0,0};
    const unsigned short* hrow = hprev + (size_t)(w * 16 + lr) * HH + hi * 8;

#pragma unroll 4
    for (int k0 = 0; k0 < HH; k0 += 32){
      bf16x8 b = *(const bf16x8*)(hrow + k0);
      int swz = (k0 * 2 + hi * 16) ^ ((lr & 7) << 4);
      bf16x8 a_r = *(const bf16x8*)(wlds +          lr * 2048 + swz);
      bf16x8 a_z = *(const bf16x8*)(wlds + 32768 +  lr * 2048 + swz);
      bf16x8 a_n = *(const bf16x8*)(wlds + 65536 +  lr * 2048 + swz);
      ar = __builtin_amdgcn_mfma_f32_16x16x32_bf16(a_r, b, ar, 0, 0, 0);
      az = __builtin_amdgcn_mfma_f32_16x16x32_bf16(a_z, b, az, 0, 0, 0);
      an = __builtin_amdgcn_mfma_f32_16x16x32_bf16(a_n, b, an, 0, 0, 0);
    }

    // ---- epilogue: gates + h update for (n, jcol..jcol+3) ----
    {
      size_t gbase = (size_t)(t * NB + n) * NCOL + (size_t)d * G3 + jcol;
      ushort4 gr4 = *(const ushort4*)(gi + gbase);
      ushort4 gz4 = *(const ushort4*)(gi + gbase + HH);
      ushort4 gn4 = *(const ushort4*)(gi + gbase + 2 * HH);
      float4 hold4 = *(const float4*)(hfprev + (size_t)n * HH + jcol);

      float hn[4]; ushort4 hb_;
      const float* br = (const float*)&br4;
      const float* bz = (const float*)&bz4;
      const float* bn_ = (const float*)&bn4;
      const float* ho = (const float*)&hold4;
      const unsigned short* g_r = (const unsigned short*)&gr4;
      const unsigned short* g_z = (const unsigned short*)&gz4;
      const unsigned short* g_n = (const unsigned short*)&gn4;
#pragma unroll
      for (int reg = 0; reg < 4; ++reg){
        float r  = sigmoidf(bf2f(g_r[reg]) + ar[reg] + br[reg]);
        float z  = sigmoidf(bf2f(g_z[reg]) + az[reg] + bz[reg]);
        float nn = tanhf(bf2f(g_n[reg]) + r * (an[reg] + bn_[reg]));
        hn[reg] = (1.f - z) * nn + z * ho[reg];
      }
      hb_.x = f2bf(hn[0]); hb_.y = f2bf(hn[1]); hb_.z = f2bf(hn[2]); hb_.w = f2bf(hn[3]);
      *(float4*)(hfnext + (size_t)n * HH + jcol) = make_float4(hn[0], hn[1], hn[2], hn[3]);
      *(ushort4*)(hbnext + (size_t)n * HH + jcol) = hb_;
      if (wout)
        *(ushort4*)(outb + (size_t)(t * NB + n) * (2 * HH) + (size_t)d * HH + jcol) = hb_;
    }

    // ---- grid barrier (flag per block, monotonic target t+1) ----
    __threadfence();
    __syncthreads();
    if (threadIdx.x == 0)
      __hip_atomic_store(&flags[blockIdx.x], t + 1, __ATOMIC_RELEASE, __HIP_MEMORY_SCOPE_AGENT);
    if (w == 0){
      int cap = 0;
      while (cap < 50000000){
        int f1 = __hip_atomic_load(&flags[l],      __ATOMIC_RELAXED, __HIP_MEMORY_SCOPE_AGENT);
        int f2 = __hip_atomic_load(&flags[l + 64], __ATOMIC_RELAXED, __HIP_MEMORY_SCOPE_AGENT);
        if (__all(f1 >= t + 1 && f2 >= t + 1)) break;
        ++cap;
      }
    }
    __syncthreads();
    __threadfence();
  }
}

// ---- final FC ----
__global__ void fc_kernel(const float* __restrict__ hf, const float* __restrict__ fw,
                          const float* __restrict__ fb, float* __restrict__ out){
  int b = blockIdx.x;
  int n = b / NC, c = b - n * NC;
  int l = threadIdx.x;
  float s = 0.f;
  for (int k = l; k < 2 * HH; k += 64){
    float hv = (k < HH) ? hf[(size_t)n * HH + k]
                        : hf[(size_t)(NB + n) * HH + (k - HH)];
    s += hv * fw[(size_t)c * (2 * HH) + k];
  }
#pragma unroll
  for (int off = 32; off > 0; off >>= 1) s += __shfl_down(s, off);
  if (l == 0) out[n * NC + c] = s + fb[c];
}

extern "C" void kernel_launch(void* const* d_in, const int* in_sizes, int n_in,
                              void* d_out, int out_size, void* d_ws, size_t ws_size,
                              hipStream_t stream)
{
  const float* x      = (const float*)d_in[0];
  const float* gamma  = (const float*)d_in[1];
  const float* beta   = (const float*)d_in[2];
  const float* w_ih0  = (const float*)d_in[3];
  const float* w_hh0  = (const float*)d_in[4];
  const float* b_ih0  = (const float*)d_in[5];
  const float* b_hh0  = (const float*)d_in[6];
  const float* w_ih   = (const float*)d_in[7];
  const float* w_hh   = (const float*)d_in[8];
  const float* b_ih   = (const float*)d_in[9];
  const float* b_hh   = (const float*)d_in[10];
  const float* fc_w   = (const float*)d_in[11];
  const float* fc_b   = (const float*)d_in[12];
  float* out = (float*)d_out;

  char* ws = (char*)d_ws;
  size_t off = 0;
  auto alloc = [&](size_t bytes)->void*{
    void* p = ws + off; off += (bytes + 255) & ~(size_t)255; return p;
  };
  unsigned short* whh_bf = (unsigned short*)alloc((size_t)3 * 2 * G3 * HH * 2);
  unsigned short* w0_bf  = (unsigned short*)alloc((size_t)NCOL * KP0 * 2);
  unsigned short* wih_bf = (unsigned short*)alloc((size_t)2 * NCOL * 2 * HH * 2);
  unsigned short* xn_bf  = (unsigned short*)alloc((size_t)RT * KP0 * 2);
  unsigned short* gi_bf  = (unsigned short*)alloc((size_t)RT * NCOL * 2);
  unsigned short* out0   = (unsigned short*)alloc((size_t)RT * 2 * HH * 2);
  unsigned short* out1   = (unsigned short*)alloc((size_t)RT * 2 * HH * 2);
  float* hf0 = (float*)alloc((size_t)2 * NB * HH * 4);
  float* hf1 = (float*)alloc((size_t)2 * NB * HH * 4);
  unsigned short* hb0 = (unsigned short*)alloc((size_t)2 * NB * HH * 2);
  unsigned short* hb1 = (unsigned short*)alloc((size_t)2 * NB * HH * 2);
  float* ss = (float*)alloc(2048);
  int* flags = (int*)alloc(1024);

  if (off > ws_size){ guard_k<<<1, 1, 0, stream>>>(out); return; }

  // BN + casts
  bn_stats<<<CIN, 256, 0, stream>>>(x, gamma, beta, ss);
  bn_apply<<<(RT * KP0 + 255) / 256, 256, 0, stream>>>(x, ss, xn_bf);
  cast_pad_w0<<<(NCOL * KP0 + 255) / 256, 256, 0, stream>>>(w_ih0, w0_bf);
  cast_bf<<<4096, 256, 0, stream>>>(w_hh0, whh_bf, 2 * G3 * HH);
  cast_bf<<<4096, 256, 0, stream>>>(w_hh,  whh_bf + (size_t)2 * G3 * HH, 2 * 2 * G3 * HH);
  cast_bf<<<4096, 256, 0, stream>>>(w_ih,  wih_bf, 2 * NCOL * 2 * HH);

  for (int lyr = 0; lyr < 3; ++lyr){
    if (lyr == 0){
      gemm_gi<<<dim3(RT / 64, NCOL / 64), 256, 0, stream>>>(xn_bf, w0_bf, b_ih0, gi_bf, KP0);
    } else {
      const unsigned short* Ain = (lyr == 1) ? out0 : out1;
      gemm_gi<<<dim3(RT / 64, NCOL / 64), 256, 0, stream>>>(
          Ain, wih_bf + (size_t)(lyr - 1) * NCOL * 2 * HH,
          b_ih + (size_t)(lyr - 1) * NCOL, gi_bf, 2 * HH);
    }
    zero16<<<128, 256, 0, stream>>>((uint4*)hf0, 2 * NB * HH * 4 / 16);
    zero16<<<64, 256, 0, stream>>>((uint4*)hb0, 2 * NB * HH * 2 / 16);
    zero16<<<1, 32, 0, stream>>>((uint4*)flags, 1024 / 16);

    const unsigned short* whh_l = whh_bf + (size_t)lyr * 2 * G3 * HH;
    const float* bhh_l = (lyr == 0) ? b_hh0 : (b_hh + (size_t)(lyr - 1) * NCOL);
    unsigned short* outb = (lyr == 0) ? out0 : out1;
    int wout = (lyr < 2) ? 1 : 0;
    gru_layer<<<128, 256, 0, stream>>>(whh_l, bhh_l, gi_bf, outb,
                                       hf0, hf1, hb0, hb1, flags, wout);
  }
  fc_kernel<<<NB * NC, 64, 0, stream>>>(hf0, fc_w, fc_b, out);
}

// Round 4
// 11548.752 us; speedup vs baseline: 1.9911x; 1.7413x over previous
//
#include <hip/hip_runtime.h>
#include <math.h>

// ---- problem constants ----
#define NB   64      // batch
#define TT   150     // timesteps
#define CIN  150
#define HH   1024
#define G3   3072    // 3*H
#define NCOL 6144    // 2*3072 (both directions)
#define KP0  160     // CIN padded to mult of 32
#define RT   9600    // T*N rows
#define NC   60

using bf16x8 = __attribute__((ext_vector_type(8))) __bf16;
using f32x4  = __attribute__((ext_vector_type(4))) float;

static __device__ __forceinline__ unsigned short f2bf(float f){
  unsigned int x = __builtin_bit_cast(unsigned int, f);
  x += 0x7fffu + ((x >> 16) & 1u);          // RNE
  return (unsigned short)(x >> 16);
}
static __device__ __forceinline__ float bf2f(unsigned short u){
  unsigned int x = ((unsigned int)u) << 16;
  return __builtin_bit_cast(float, x);
}
static __device__ __forceinline__ float sigmoidf(float x){
  return 1.0f / (1.0f + expf(-x));
}

// ---- BatchNorm stats: one block per channel ----
__global__ void bn_stats(const float* __restrict__ x, const float* __restrict__ gamma,
                         const float* __restrict__ beta, float* __restrict__ ss){
  const int c = blockIdx.x;
  float s = 0.f, s2 = 0.f;
  for (int i = threadIdx.x; i < RT; i += 256){
    float v = x[(size_t)i * CIN + c];
    s += v; s2 += v * v;
  }
  __shared__ float sh1[256], sh2[256];
  sh1[threadIdx.x] = s; sh2[threadIdx.x] = s2;
  __syncthreads();
  for (int st = 128; st > 0; st >>= 1){
    if ((int)threadIdx.x < st){
      sh1[threadIdx.x] += sh1[threadIdx.x + st];
      sh2[threadIdx.x] += sh2[threadIdx.x + st];
    }
    __syncthreads();
  }
  if (threadIdx.x == 0){
    float mean = sh1[0] * (1.f / RT);
    float var  = sh2[0] * (1.f / RT) - mean * mean;
    float sc   = rsqrtf(var + 1e-5f) * gamma[c];
    ss[c]       = sc;
    ss[CIN + c] = beta[c] - mean * sc;
  }
}

// ---- normalize + transpose [N,T,C] -> bf16 [t*64+n, KP0] with zero pad ----
__global__ void bn_apply(const float* __restrict__ x, const float* __restrict__ ss,
                         unsigned short* __restrict__ xn){
  int idx = blockIdx.x * 256 + threadIdx.x;
  if (idx >= RT * KP0) return;
  int r = idx / KP0, c = idx - r * KP0;
  int t = r >> 6, n = r & 63;
  float v = 0.f;
  if (c < CIN) v = x[((size_t)n * TT + t) * CIN + c] * ss[c] + ss[CIN + c];
  xn[idx] = f2bf(v);
}

// ---- cast fp32 -> bf16 (grid stride) ----
__global__ void cast_bf(const float* __restrict__ s, unsigned short* __restrict__ d, int n){
  for (int i = blockIdx.x * 256 + threadIdx.x; i < n; i += gridDim.x * 256)
    d[i] = f2bf(s[i]);
}

// ---- cast + pad w_ih0 [6144,150] -> [6144,160] bf16 ----
__global__ void cast_pad_w0(const float* __restrict__ w, unsigned short* __restrict__ d){
  int idx = blockIdx.x * 256 + threadIdx.x;
  if (idx >= NCOL * KP0) return;
  int row = idx / KP0, c = idx - row * KP0;
  d[idx] = (c < CIN) ? f2bf(w[(size_t)row * CIN + c]) : (unsigned short)0;
}

__global__ void zero16(uint4* p, int n){
  int i = blockIdx.x * 256 + threadIdx.x;
  if (i < n) p[i] = make_uint4(0u, 0u, 0u, 0u);
}

__global__ void guard_k(float* out){ out[0] = -12345.0f; }

// ---- gi GEMM: C[r, col] = sum_k A[r,k]*B[col,k] + bias[col], bf16 in/out, f32 acc
__global__ __launch_bounds__(256) void gemm_gi(
    const unsigned short* __restrict__ A, const unsigned short* __restrict__ B,
    const float* __restrict__ bias, unsigned short* __restrict__ C, int K)
{
  const int r0 = blockIdx.x * 64;
  const int c0 = blockIdx.y * 64;
  const int w  = threadIdx.x >> 6;
  const int l  = threadIdx.x & 63;
  const int lr = l & 15;
  const int lk = (l >> 4) * 8;
  const int col = c0 + 16 * w + lr;

  f32x4 acc[4] = {f32x4{0,0,0,0}, f32x4{0,0,0,0}, f32x4{0,0,0,0}, f32x4{0,0,0,0}};
  const unsigned short* Ab = A + (size_t)(r0 + lr) * K + lk;
  const unsigned short* Bb = B + (size_t)col * K + lk;

  for (int k0 = 0; k0 < K; k0 += 32){
    bf16x8 b = *(const bf16x8*)(Bb + k0);
#pragma unroll
    for (int mt = 0; mt < 4; ++mt){
      bf16x8 a = *(const bf16x8*)(Ab + (size_t)mt * 16 * K + k0);
      acc[mt] = __builtin_amdgcn_mfma_f32_16x16x32_bf16(a, b, acc[mt], 0, 0, 0);
    }
  }
  const float bv = bias[col];
  const int rb = (l >> 4) * 4;
#pragma unroll
  for (int mt = 0; mt < 4; ++mt){
#pragma unroll
    for (int reg = 0; reg < 4; ++reg){
      int row = r0 + 16 * mt + rb + reg;
      C[(size_t)row * NCOL + col] = f2bf(acc[mt][reg] + bv);
    }
  }
}

// ================= persistent GRU layer =================
// grid 128 = 2 dirs x 64 col-tiles (16 hidden cols each), block 256 (4 waves).
// Weights (3 gates x 16 cols x 1024) in LDS (96KB, slot-rotation layout).
// Coherence: hb (bf16 h) crosses blocks -> relaxed agent atomic 8B stores
// (write-through); flags release/acquire; ONE buffer_inv per step via
// acquire fence; hf master state is block-local (plain cached).
__global__ __launch_bounds__(256, 1) void gru_layer(
    const unsigned short* __restrict__ whh,   // [2][3072][1024] bf16
    const float* __restrict__ bhh,            // [2][3072]
    const unsigned short* __restrict__ gi,    // [9600][6144] bf16
    unsigned short* __restrict__ outb,        // [9600][2048] bf16 (may be unused)
    float* __restrict__ hf0, float* __restrict__ hf1,             // [2][64][1024] f32
    unsigned short* __restrict__ hb0, unsigned short* __restrict__ hb1, // bf16
    int* __restrict__ flags, int wout)
{
  const int d  = blockIdx.x >> 6;
  const int jt = blockIdx.x & 63;
  const int j0 = jt * 16;
  const int w  = threadIdx.x >> 6;
  const int l  = threadIdx.x & 63;
  const int lr = l & 15;
  const int hi = l >> 4;

  __shared__ unsigned char wlds[98304];   // 3 planes of 32KB: [16 rows][2048B]

  // ---- load weight slice to LDS (once). Slot-rotation layout:
  // 16B-chunk kc within a row r stored at kc' = (kc & ~7) | ((kc + r) & 7).
  {
    const unsigned short* wsrc = whh + (size_t)d * (G3 * HH);
    for (int c = threadIdx.x; c < 6144; c += 256){     // 16B chunks
      int g   = c >> 11;
      int rem = c & 2047;
      int r   = rem >> 7;
      int kc  = rem & 127;
      uint4 v = *(const uint4*)(wsrc + (size_t)(g * HH + j0 + r) * HH + kc * 8);
      int kcs = (kc & ~7) | ((kc + r) & 7);
      *(uint4*)(wlds + g * 32768 + r * 2048 + kcs * 16) = v;
    }
  }
  __syncthreads();

  // biases for this lane's 4 gate-cols (gc = j0 + hi*4 + reg)
  const float4 br4 = *(const float4*)(bhh + d * G3 +          j0 + hi * 4);
  const float4 bz4 = *(const float4*)(bhh + d * G3 + HH +     j0 + hi * 4);
  const float4 bn4 = *(const float4*)(bhh + d * G3 + 2 * HH + j0 + hi * 4);

  const int n    = w * 16 + lr;            // batch row this lane handles in epilogue
  const int jcol = j0 + hi * 4;            // first of 4 hidden cols this lane handles

  for (int t = 0; t < TT; ++t){
    const unsigned short* hprev = ((t & 1) ? hb1 : hb0) + (size_t)d * (NB * HH);
    const float*  hfprev = ((t & 1) ? hf1 : hf0) + (size_t)d * (NB * HH);
    float*        hfnext = ((t & 1) ? hf0 : hf1) + (size_t)d * (NB * HH);
    unsigned short* hbnext = ((t & 1) ? hb0 : hb1) + (size_t)d * (NB * HH);

    // ---- prefetch h-independent operands (hides post-inv L3 latency) ----
    size_t gbase = (size_t)(t * NB + n) * NCOL + (size_t)d * G3 + jcol;
    ushort4 gr4 = *(const ushort4*)(gi + gbase);
    ushort4 gz4 = *(const ushort4*)(gi + gbase + HH);
    ushort4 gn4 = *(const ushort4*)(gi + gbase + 2 * HH);
    float4 hold4 = *(const float4*)(hfprev + (size_t)n * HH + jcol);

    f32x4 ar = {0,0,0,0}, az = {0,0,0,0}, an = {0,0,0,0};
    const unsigned short* hrow = hprev + (size_t)(w * 16 + lr) * HH + hi * 8;

#pragma unroll 4
    for (int k0 = 0; k0 < HH; k0 += 32){
      bf16x8 b = *(const bf16x8*)(hrow + k0);
      int kc  = (k0 >> 3) + hi;                       // 16B chunk index
      int kcs = (kc & ~7) | ((kc + lr) & 7);
      int off = lr * 2048 + kcs * 16;
      bf16x8 a_r = *(const bf16x8*)(wlds +          off);
      bf16x8 a_z = *(const bf16x8*)(wlds + 32768 +  off);
      bf16x8 a_n = *(const bf16x8*)(wlds + 65536 +  off);
      ar = __builtin_amdgcn_mfma_f32_16x16x32_bf16(a_r, b, ar, 0, 0, 0);
      az = __builtin_amdgcn_mfma_f32_16x16x32_bf16(a_z, b, az, 0, 0, 0);
      an = __builtin_amdgcn_mfma_f32_16x16x32_bf16(a_n, b, an, 0, 0, 0);
    }

    // ---- epilogue: gates + h update for (n, jcol..jcol+3) ----
    {
      float hn[4]; ushort4 hb_;
      const float* br = (const float*)&br4;
      const float* bz = (const float*)&bz4;
      const float* bn_ = (const float*)&bn4;
      const float* ho = (const float*)&hold4;
      const unsigned short* g_r = (const unsigned short*)&gr4;
      const unsigned short* g_z = (const unsigned short*)&gz4;
      const unsigned short* g_n = (const unsigned short*)&gn4;
#pragma unroll
      for (int reg = 0; reg < 4; ++reg){
        float r  = sigmoidf(bf2f(g_r[reg]) + ar[reg] + br[reg]);
        float z  = sigmoidf(bf2f(g_z[reg]) + az[reg] + bz[reg]);
        float nn = tanhf(bf2f(g_n[reg]) + r * (an[reg] + bn_[reg]));
        hn[reg] = (1.f - z) * nn + z * ho[reg];
      }
      hb_.x = f2bf(hn[0]); hb_.y = f2bf(hn[1]); hb_.z = f2bf(hn[2]); hb_.w = f2bf(hn[3]);
      *(float4*)(hfnext + (size_t)n * HH + jcol) = make_float4(hn[0], hn[1], hn[2], hn[3]);
      if (wout)
        *(ushort4*)(outb + (size_t)(t * NB + n) * (2 * HH) + (size_t)d * HH + jcol) = hb_;
      // device-visible (write-through) h for other blocks:
      __hip_atomic_store((unsigned long long*)(hbnext + (size_t)n * HH + jcol),
                         __builtin_bit_cast(unsigned long long, hb_),
                         __ATOMIC_RELAXED, __HIP_MEMORY_SCOPE_AGENT);
    }

    // ---- grid barrier: release own flag, wait on own direction's 64 ----
    __syncthreads();   // drains vmem (incl. hb atomics) before flag release
    if (threadIdx.x == 0)
      __hip_atomic_store(&flags[blockIdx.x], t + 1, __ATOMIC_RELEASE, __HIP_MEMORY_SCOPE_AGENT);
    if (w == 0){
      const int* myfl = flags + d * 64;
      int cap = 0;
      while (cap < 100000000){
        int f = __hip_atomic_load(&myfl[l], __ATOMIC_RELAXED, __HIP_MEMORY_SCOPE_AGENT);
        if (__all(f >= t + 1)) break;
        ++cap;
      }
    }
    __syncthreads();
    // one L2 invalidate per step so next step's plain hb reads see fresh data
    __builtin_amdgcn_fence(__ATOMIC_ACQUIRE, "agent");
  }
}

// ---- final FC ----
__global__ void fc_kernel(const float* __restrict__ hf, const float* __restrict__ fw,
                          const float* __restrict__ fb, float* __restrict__ out){
  int b = blockIdx.x;
  int n = b / NC, c = b - n * NC;
  int l = threadIdx.x;
  float s = 0.f;
  for (int k = l; k < 2 * HH; k += 64){
    float hv = (k < HH) ? hf[(size_t)n * HH + k]
                        : hf[(size_t)(NB + n) * HH + (k - HH)];
    s += hv * fw[(size_t)c * (2 * HH) + k];
  }
#pragma unroll
  for (int off = 32; off > 0; off >>= 1) s += __shfl_down(s, off);
  if (l == 0) out[n * NC + c] = s + fb[c];
}

extern "C" void kernel_launch(void* const* d_in, const int* in_sizes, int n_in,
                              void* d_out, int out_size, void* d_ws, size_t ws_size,
                              hipStream_t stream)
{
  const float* x      = (const float*)d_in[0];
  const float* gamma  = (const float*)d_in[1];
  const float* beta   = (const float*)d_in[2];
  const float* w_ih0  = (const float*)d_in[3];
  const float* w_hh0  = (const float*)d_in[4];
  const float* b_ih0  = (const float*)d_in[5];
  const float* b_hh0  = (const float*)d_in[6];
  const float* w_ih   = (const float*)d_in[7];
  const float* w_hh   = (const float*)d_in[8];
  const float* b_ih   = (const float*)d_in[9];
  const float* b_hh   = (const float*)d_in[10];
  const float* fc_w   = (const float*)d_in[11];
  const float* fc_b   = (const float*)d_in[12];
  float* out = (float*)d_out;

  char* ws = (char*)d_ws;
  size_t off = 0;
  auto alloc = [&](size_t bytes)->void*{
    void* p = ws + off; off += (bytes + 255) & ~(size_t)255; return p;
  };
  unsigned short* whh_bf = (unsigned short*)alloc((size_t)3 * 2 * G3 * HH * 2);
  unsigned short* w0_bf  = (unsigned short*)alloc((size_t)NCOL * KP0 * 2);
  unsigned short* wih_bf = (unsigned short*)alloc((size_t)2 * NCOL * 2 * HH * 2);
  unsigned short* xn_bf  = (unsigned short*)alloc((size_t)RT * KP0 * 2);
  unsigned short* gi_bf  = (unsigned short*)alloc((size_t)RT * NCOL * 2);
  unsigned short* out0   = (unsigned short*)alloc((size_t)RT * 2 * HH * 2);
  unsigned short* out1   = (unsigned short*)alloc((size_t)RT * 2 * HH * 2);
  float* hf0 = (float*)alloc((size_t)2 * NB * HH * 4);
  float* hf1 = (float*)alloc((size_t)2 * NB * HH * 4);
  unsigned short* hb0 = (unsigned short*)alloc((size_t)2 * NB * HH * 2);
  unsigned short* hb1 = (unsigned short*)alloc((size_t)2 * NB * HH * 2);
  float* ss = (float*)alloc(2048);
  int* flags = (int*)alloc(1024);

  if (off > ws_size){ guard_k<<<1, 1, 0, stream>>>(out); return; }

  // BN + casts
  bn_stats<<<CIN, 256, 0, stream>>>(x, gamma, beta, ss);
  bn_apply<<<(RT * KP0 + 255) / 256, 256, 0, stream>>>(x, ss, xn_bf);
  cast_pad_w0<<<(NCOL * KP0 + 255) / 256, 256, 0, stream>>>(w_ih0, w0_bf);
  cast_bf<<<4096, 256, 0, stream>>>(w_hh0, whh_bf, 2 * G3 * HH);
  cast_bf<<<4096, 256, 0, stream>>>(w_hh,  whh_bf + (size_t)2 * G3 * HH, 2 * 2 * G3 * HH);
  cast_bf<<<4096, 256, 0, stream>>>(w_ih,  wih_bf, 2 * NCOL * 2 * HH);

  for (int lyr = 0; lyr < 3; ++lyr){
    if (lyr == 0){
      gemm_gi<<<dim3(RT / 64, NCOL / 64), 256, 0, stream>>>(xn_bf, w0_bf, b_ih0, gi_bf, KP0);
    } else {
      const unsigned short* Ain = (lyr == 1) ? out0 : out1;
      gemm_gi<<<dim3(RT / 64, NCOL / 64), 256, 0, stream>>>(
          Ain, wih_bf + (size_t)(lyr - 1) * NCOL * 2 * HH,
          b_ih + (size_t)(lyr - 1) * NCOL, gi_bf, 2 * HH);
    }
    zero16<<<128, 256, 0, stream>>>((uint4*)hf0, 2 * NB * HH * 4 / 16);
    zero16<<<64, 256, 0, stream>>>((uint4*)hb0, 2 * NB * HH * 2 / 16);
    zero16<<<1, 32, 0, stream>>>((uint4*)flags, 1024 / 16);

    const unsigned short* whh_l = whh_bf + (size_t)lyr * 2 * G3 * HH;
    const float* bhh_l = (lyr == 0) ? b_hh0 : (b_hh + (size_t)(lyr - 1) * NCOL);
    unsigned short* outb = (lyr == 0) ? out0 : out1;
    int wout = (lyr < 2) ? 1 : 0;
    gru_layer<<<128, 256, 0, stream>>>(whh_l, bhh_l, gi_bf, outb,
                                       hf0, hf1, hb0, hb1, flags, wout);
  }
  fc_kernel<<<NB * NC, 64, 0, stream>>>(hf0, fc_w, fc_b, out);
}

// Round 5
// 10216.450 us; speedup vs baseline: 2.2507x; 1.1304x over previous
//
#include <hip/hip_runtime.h>
#include <math.h>

// ---- problem constants ----
#define NB   64      // batch
#define TT   150     // timesteps
#define CIN  150
#define HH   1024
#define G3   3072    // 3*H
#define NCOL 6144    // 2*3072 (both directions)
#define KP0  160     // CIN padded to mult of 32
#define RT   9600    // T*N rows
#define NC   60

using bf16x8 = __attribute__((ext_vector_type(8))) __bf16;
using f32x4  = __attribute__((ext_vector_type(4))) float;

static __device__ __forceinline__ unsigned short f2bf(float f){
  unsigned int x = __builtin_bit_cast(unsigned int, f);
  x += 0x7fffu + ((x >> 16) & 1u);          // RNE
  return (unsigned short)(x >> 16);
}
static __device__ __forceinline__ float bf2f(unsigned short u){
  unsigned int x = ((unsigned int)u) << 16;
  return __builtin_bit_cast(float, x);
}
static __device__ __forceinline__ float sigmoidf(float x){
  return 1.0f / (1.0f + expf(-x));
}

// ---- BatchNorm stats: one block per channel ----
__global__ void bn_stats(const float* __restrict__ x, const float* __restrict__ gamma,
                         const float* __restrict__ beta, float* __restrict__ ss){
  const int c = blockIdx.x;
  float s = 0.f, s2 = 0.f;
  for (int i = threadIdx.x; i < RT; i += 256){
    float v = x[(size_t)i * CIN + c];
    s += v; s2 += v * v;
  }
  __shared__ float sh1[256], sh2[256];
  sh1[threadIdx.x] = s; sh2[threadIdx.x] = s2;
  __syncthreads();
  for (int st = 128; st > 0; st >>= 1){
    if ((int)threadIdx.x < st){
      sh1[threadIdx.x] += sh1[threadIdx.x + st];
      sh2[threadIdx.x] += sh2[threadIdx.x + st];
    }
    __syncthreads();
  }
  if (threadIdx.x == 0){
    float mean = sh1[0] * (1.f / RT);
    float var  = sh2[0] * (1.f / RT) - mean * mean;
    float sc   = rsqrtf(var + 1e-5f) * gamma[c];
    ss[c]       = sc;
    ss[CIN + c] = beta[c] - mean * sc;
  }
}

// ---- normalize + transpose [N,T,C] -> bf16 [t*64+n, KP0] with zero pad ----
__global__ void bn_apply(const float* __restrict__ x, const float* __restrict__ ss,
                         unsigned short* __restrict__ xn){
  int idx = blockIdx.x * 256 + threadIdx.x;
  if (idx >= RT * KP0) return;
  int r = idx / KP0, c = idx - r * KP0;
  int t = r >> 6, n = r & 63;
  float v = 0.f;
  if (c < CIN) v = x[((size_t)n * TT + t) * CIN + c] * ss[c] + ss[CIN + c];
  xn[idx] = f2bf(v);
}

// ---- cast fp32 -> bf16 (grid stride) ----
__global__ void cast_bf(const float* __restrict__ s, unsigned short* __restrict__ d, int n){
  for (int i = blockIdx.x * 256 + threadIdx.x; i < n; i += gridDim.x * 256)
    d[i] = f2bf(s[i]);
}

// ---- cast + pad w_ih0 [6144,150] -> [6144,160] bf16 ----
__global__ void cast_pad_w0(const float* __restrict__ w, unsigned short* __restrict__ d){
  int idx = blockIdx.x * 256 + threadIdx.x;
  if (idx >= NCOL * KP0) return;
  int row = idx / KP0, c = idx - row * KP0;
  d[idx] = (c < CIN) ? f2bf(w[(size_t)row * CIN + c]) : (unsigned short)0;
}

__global__ void zero16(uint4* p, int n){
  int i = blockIdx.x * 256 + threadIdx.x;
  if (i < n) p[i] = make_uint4(0u, 0u, 0u, 0u);
}

__global__ void guard_k(float* out){ out[0] = -12345.0f; }

// ---- gi GEMM: C[r, col] = sum_k A[r,k]*B[col,k] + bias[col], bf16 in/out, f32 acc
__global__ __launch_bounds__(256) void gemm_gi(
    const unsigned short* __restrict__ A, const unsigned short* __restrict__ B,
    const float* __restrict__ bias, unsigned short* __restrict__ C, int K)
{
  const int r0 = blockIdx.x * 64;
  const int c0 = blockIdx.y * 64;
  const int w  = threadIdx.x >> 6;
  const int l  = threadIdx.x & 63;
  const int lr = l & 15;
  const int lk = (l >> 4) * 8;
  const int col = c0 + 16 * w + lr;

  f32x4 acc[4] = {f32x4{0,0,0,0}, f32x4{0,0,0,0}, f32x4{0,0,0,0}, f32x4{0,0,0,0}};
  const unsigned short* Ab = A + (size_t)(r0 + lr) * K + lk;
  const unsigned short* Bb = B + (size_t)col * K + lk;

  for (int k0 = 0; k0 < K; k0 += 32){
    bf16x8 b = *(const bf16x8*)(Bb + k0);
#pragma unroll
    for (int mt = 0; mt < 4; ++mt){
      bf16x8 a = *(const bf16x8*)(Ab + (size_t)mt * 16 * K + k0);
      acc[mt] = __builtin_amdgcn_mfma_f32_16x16x32_bf16(a, b, acc[mt], 0, 0, 0);
    }
  }
  const float bv = bias[col];
  const int rb = (l >> 4) * 4;
#pragma unroll
  for (int mt = 0; mt < 4; ++mt){
#pragma unroll
    for (int reg = 0; reg < 4; ++reg){
      int row = r0 + 16 * mt + rb + reg;
      C[(size_t)row * NCOL + col] = f2bf(acc[mt][reg] + bv);
    }
  }
}

// ================= persistent GRU layer =================
// grid 128 = 2 dirs x 64 col-tiles (16 hidden cols each), block 256 (4 waves).
// Weights (3 gates x 16 cols x 1024) in LDS (96KB, slot-rotation layout).
// Cross-block h exchange: agent-scope relaxed 8B atomics BOTH ways (stores
// write through; loads read at coherence point) -> NO cache fences at all.
// fp32 h master stays in registers (same lane owns same (n,jcol) all steps).
__global__ __launch_bounds__(256, 1) void gru_layer(
    const unsigned short* __restrict__ whh,   // [2][3072][1024] bf16
    const float* __restrict__ bhh,            // [2][3072]
    const unsigned short* __restrict__ gi,    // [9600][6144] bf16
    unsigned short* __restrict__ outb,        // [9600][2048] bf16 (may be unused)
    float* __restrict__ hfinal,               // [2][64][1024] f32 (written at t=149)
    unsigned short* __restrict__ hb0, unsigned short* __restrict__ hb1, // bf16
    int* __restrict__ flags, int wout)
{
  const int d  = blockIdx.x >> 6;
  const int jt = blockIdx.x & 63;
  const int j0 = jt * 16;
  const int w  = threadIdx.x >> 6;
  const int l  = threadIdx.x & 63;
  const int lr = l & 15;
  const int hi = l >> 4;

  __shared__ unsigned char wlds[98304];   // 3 planes of 32KB: [16 rows][2048B]

  // ---- load weight slice to LDS (once). Slot-rotation layout:
  // 16B-chunk kc within a row r stored at kc' = (kc & ~7) | ((kc + r) & 7).
  {
    const unsigned short* wsrc = whh + (size_t)d * (G3 * HH);
    for (int c = threadIdx.x; c < 6144; c += 256){     // 16B chunks
      int g   = c >> 11;
      int rem = c & 2047;
      int r   = rem >> 7;
      int kc  = rem & 127;
      uint4 v = *(const uint4*)(wsrc + (size_t)(g * HH + j0 + r) * HH + kc * 8);
      int kcs = (kc & ~7) | ((kc + r) & 7);
      *(uint4*)(wlds + g * 32768 + r * 2048 + kcs * 16) = v;
    }
  }
  __syncthreads();

  // biases for this lane's 4 gate-cols (gc = j0 + hi*4 + reg)
  const float4 br4 = *(const float4*)(bhh + d * G3 +          j0 + hi * 4);
  const float4 bz4 = *(const float4*)(bhh + d * G3 + HH +     j0 + hi * 4);
  const float4 bn4 = *(const float4*)(bhh + d * G3 + 2 * HH + j0 + hi * 4);

  const int n    = w * 16 + lr;            // batch row this lane handles in epilogue
  const int jcol = j0 + hi * 4;            // first of 4 hidden cols this lane handles

  float hold[4] = {0.f, 0.f, 0.f, 0.f};    // fp32 master h for (n, jcol..+3)

  for (int t = 0; t < TT; ++t){
    const unsigned short* hprev = ((t & 1) ? hb1 : hb0) + (size_t)d * (NB * HH);
    unsigned short* hbnext = ((t & 1) ? hb0 : hb1) + (size_t)d * (NB * HH);

    // ---- prefetch gi (h-independent; L2-warm) ----
    size_t gbase = (size_t)(t * NB + n) * NCOL + (size_t)d * G3 + jcol;
    ushort4 gr4 = *(const ushort4*)(gi + gbase);
    ushort4 gz4 = *(const ushort4*)(gi + gbase + HH);
    ushort4 gn4 = *(const ushort4*)(gi + gbase + 2 * HH);

    f32x4 ar = {0,0,0,0}, az = {0,0,0,0}, an = {0,0,0,0};
    // this wave's h rows, 8B-quantized: lane reads bf16 [k0+hi*8 .. +8)
    const unsigned long long* hq =
        (const unsigned long long*)(hprev + (size_t)(w * 16 + lr) * HH) + 2 * hi;

#pragma unroll 4
    for (int k0 = 0; k0 < HH; k0 += 32){
      unsigned long long q0 = __hip_atomic_load(hq + (k0 >> 2),
                              __ATOMIC_RELAXED, __HIP_MEMORY_SCOPE_AGENT);
      unsigned long long q1 = __hip_atomic_load(hq + (k0 >> 2) + 1,
                              __ATOMIC_RELAXED, __HIP_MEMORY_SCOPE_AGENT);
      union { unsigned long long q[2]; bf16x8 v; } ub;
      ub.q[0] = q0; ub.q[1] = q1;
      bf16x8 b = ub.v;
      int kc  = (k0 >> 3) + hi;                       // 16B chunk index
      int kcs = (kc & ~7) | ((kc + lr) & 7);
      int off = lr * 2048 + kcs * 16;
      bf16x8 a_r = *(const bf16x8*)(wlds +          off);
      bf16x8 a_z = *(const bf16x8*)(wlds + 32768 +  off);
      bf16x8 a_n = *(const bf16x8*)(wlds + 65536 +  off);
      ar = __builtin_amdgcn_mfma_f32_16x16x32_bf16(a_r, b, ar, 0, 0, 0);
      az = __builtin_amdgcn_mfma_f32_16x16x32_bf16(a_z, b, az, 0, 0, 0);
      an = __builtin_amdgcn_mfma_f32_16x16x32_bf16(a_n, b, an, 0, 0, 0);
    }

    // ---- epilogue: gates + h update for (n, jcol..jcol+3) ----
    {
      ushort4 hb_;
      const float* br = (const float*)&br4;
      const float* bz = (const float*)&bz4;
      const float* bn_ = (const float*)&bn4;
      const unsigned short* g_r = (const unsigned short*)&gr4;
      const unsigned short* g_z = (const unsigned short*)&gz4;
      const unsigned short* g_n = (const unsigned short*)&gn4;
#pragma unroll
      for (int reg = 0; reg < 4; ++reg){
        float r  = sigmoidf(bf2f(g_r[reg]) + ar[reg] + br[reg]);
        float z  = sigmoidf(bf2f(g_z[reg]) + az[reg] + bz[reg]);
        float nn = tanhf(bf2f(g_n[reg]) + r * (an[reg] + bn_[reg]));
        hold[reg] = (1.f - z) * nn + z * hold[reg];
      }
      hb_.x = f2bf(hold[0]); hb_.y = f2bf(hold[1]);
      hb_.z = f2bf(hold[2]); hb_.w = f2bf(hold[3]);
      if (wout)
        *(ushort4*)(outb + (size_t)(t * NB + n) * (2 * HH) + (size_t)d * HH + jcol) = hb_;
      if (t == TT - 1)
        *(float4*)(hfinal + (size_t)(d * NB + n) * HH + jcol) =
            make_float4(hold[0], hold[1], hold[2], hold[3]);
      // device-visible (write-through) h for other blocks:
      __hip_atomic_store((unsigned long long*)(hbnext + (size_t)n * HH + jcol),
                         __builtin_bit_cast(unsigned long long, hb_),
                         __ATOMIC_RELAXED, __HIP_MEMORY_SCOPE_AGENT);
    }

    // ---- grid barrier: release own flag, wait on own direction's 64 ----
    __syncthreads();   // each wave drains its vmem (incl. hb atomics) here
    if (threadIdx.x == 0)
      __hip_atomic_store(&flags[blockIdx.x], t + 1, __ATOMIC_RELEASE, __HIP_MEMORY_SCOPE_AGENT);
    if (w == 0){
      const int* myfl = flags + d * 64;
      int cap = 0;
      for (;;){
        int f = __hip_atomic_load(&myfl[l], __ATOMIC_RELAXED, __HIP_MEMORY_SCOPE_AGENT);
        if (__all(f >= t + 1)) break;
        if (++cap > 20000000) break;
        __builtin_amdgcn_s_sleep(2);   // back off; don't storm the fabric
      }
    }
    __syncthreads();
  }
}

// ---- final FC ----
__global__ void fc_kernel(const float* __restrict__ hf, const float* __restrict__ fw,
                          const float* __restrict__ fb, float* __restrict__ out){
  int b = blockIdx.x;
  int n = b / NC, c = b - n * NC;
  int l = threadIdx.x;
  float s = 0.f;
  for (int k = l; k < 2 * HH; k += 64){
    float hv = (k < HH) ? hf[(size_t)n * HH + k]
                        : hf[(size_t)(NB + n) * HH + (k - HH)];
    s += hv * fw[(size_t)c * (2 * HH) + k];
  }
#pragma unroll
  for (int off = 32; off > 0; off >>= 1) s += __shfl_down(s, off);
  if (l == 0) out[n * NC + c] = s + fb[c];
}

extern "C" void kernel_launch(void* const* d_in, const int* in_sizes, int n_in,
                              void* d_out, int out_size, void* d_ws, size_t ws_size,
                              hipStream_t stream)
{
  const float* x      = (const float*)d_in[0];
  const float* gamma  = (const float*)d_in[1];
  const float* beta   = (const float*)d_in[2];
  const float* w_ih0  = (const float*)d_in[3];
  const float* w_hh0  = (const float*)d_in[4];
  const float* b_ih0  = (const float*)d_in[5];
  const float* b_hh0  = (const float*)d_in[6];
  const float* w_ih   = (const float*)d_in[7];
  const float* w_hh   = (const float*)d_in[8];
  const float* b_ih   = (const float*)d_in[9];
  const float* b_hh   = (const float*)d_in[10];
  const float* fc_w   = (const float*)d_in[11];
  const float* fc_b   = (const float*)d_in[12];
  float* out = (float*)d_out;

  char* ws = (char*)d_ws;
  size_t off = 0;
  auto alloc = [&](size_t bytes)->void*{
    void* p = ws + off; off += (bytes + 255) & ~(size_t)255; return p;
  };
  unsigned short* whh_bf = (unsigned short*)alloc((size_t)3 * 2 * G3 * HH * 2);
  unsigned short* w0_bf  = (unsigned short*)alloc((size_t)NCOL * KP0 * 2);
  unsigned short* wih_bf = (unsigned short*)alloc((size_t)2 * NCOL * 2 * HH * 2);
  unsigned short* xn_bf  = (unsigned short*)alloc((size_t)RT * KP0 * 2);
  unsigned short* gi_bf  = (unsigned short*)alloc((size_t)RT * NCOL * 2);
  unsigned short* out0   = (unsigned short*)alloc((size_t)RT * 2 * HH * 2);
  unsigned short* out1   = (unsigned short*)alloc((size_t)RT * 2 * HH * 2);
  float* hfinal = (float*)alloc((size_t)2 * NB * HH * 4);
  unsigned short* hb0 = (unsigned short*)alloc((size_t)2 * NB * HH * 2);
  unsigned short* hb1 = (unsigned short*)alloc((size_t)2 * NB * HH * 2);
  float* ss = (float*)alloc(2048);
  int* flags = (int*)alloc(1024);

  if (off > ws_size){ guard_k<<<1, 1, 0, stream>>>(out); return; }

  // BN + casts
  bn_stats<<<CIN, 256, 0, stream>>>(x, gamma, beta, ss);
  bn_apply<<<(RT * KP0 + 255) / 256, 256, 0, stream>>>(x, ss, xn_bf);
  cast_pad_w0<<<(NCOL * KP0 + 255) / 256, 256, 0, stream>>>(w_ih0, w0_bf);
  cast_bf<<<4096, 256, 0, stream>>>(w_hh0, whh_bf, 2 * G3 * HH);
  cast_bf<<<4096, 256, 0, stream>>>(w_hh,  whh_bf + (size_t)2 * G3 * HH, 2 * 2 * G3 * HH);
  cast_bf<<<4096, 256, 0, stream>>>(w_ih,  wih_bf, 2 * NCOL * 2 * HH);

  for (int lyr = 0; lyr < 3; ++lyr){
    if (lyr == 0){
      gemm_gi<<<dim3(RT / 64, NCOL / 64), 256, 0, stream>>>(xn_bf, w0_bf, b_ih0, gi_bf, KP0);
    } else {
      const unsigned short* Ain = (lyr == 1) ? out0 : out1;
      gemm_gi<<<dim3(RT / 64, NCOL / 64), 256, 0, stream>>>(
          Ain, wih_bf + (size_t)(lyr - 1) * NCOL * 2 * HH,
          b_ih + (size_t)(lyr - 1) * NCOL, gi_bf, 2 * HH);
    }
    zero16<<<64, 256, 0, stream>>>((uint4*)hb0, 2 * NB * HH * 2 / 16);
    zero16<<<1, 32, 0, stream>>>((uint4*)flags, 512 / 16);

    const unsigned short* whh_l = whh_bf + (size_t)lyr * 2 * G3 * HH;
    const float* bhh_l = (lyr == 0) ? b_hh0 : (b_hh + (size_t)(lyr - 1) * NCOL);
    unsigned short* outb = (lyr == 0) ? out0 : out1;
    int wout = (lyr < 2) ? 1 : 0;
    gru_layer<<<128, 256, 0, stream>>>(whh_l, bhh_l, gi_bf, outb,
                                       hfinal, hb0, hb1, flags, wout);
  }
  fc_kernel<<<NB * NC, 64, 0, stream>>>(hfinal, fc_w, fc_b, out);
}